// Round 1
// baseline (130.247 us; speedup 1.0000x reference)
//
#include <hip/hip_runtime.h>

// Gaussian 3x3 conv forward, B=64, C=1, H=W=512, N_MULT=1.
// Reference collapses to: taps = max(rint(clamp(w,0.001,0.999)*clamp(wf,1.001,254.999)), 0.001)
// then 3x3 conv with zero padding=1. Output [1,64,1,512,512] fp32 (same flat layout as input).

#define BB 64
#define HH 512
#define WW 512
#define W4 (WW / 4)   // 128 float4 per row

__global__ __launch_bounds__(256) void gauss3x3_kernel(
    const float* __restrict__ in,     // [B,1,H,W]
    const float* __restrict__ wgt,    // [1,9]
    const float* __restrict__ wfac,   // [1,1]
    float* __restrict__ out)          // [1,B,1,H,W]
{
    // Derive the 9 taps (redundantly per thread; 10 scalar loads, L2-broadcast).
    float wf = fminf(fmaxf(wfac[0], 1.001f), 254.999f);
    float k[9];
#pragma unroll
    for (int i = 0; i < 9; ++i) {
        float wc = fminf(fmaxf(wgt[i], 0.001f), 0.999f);
        k[i] = fmaxf(rintf(wc * wf), 0.001f);   // rintf = round-half-even, matches jnp.round
    }

    int tid = blockIdx.x * blockDim.x + threadIdx.x;   // [0, B*H*W4)
    int x4 = tid & (W4 - 1);           // float4 index within row
    int y  = (tid >> 7) & (HH - 1);    // wave-uniform (64 lanes = half a row)
    int b  = tid >> 16;                // H*W4 = 65536
    if (b >= BB) return;

    const float* img = in + (size_t)b * HH * WW;
    const int x0 = x4 * 4;

    float4 acc = make_float4(0.f, 0.f, 0.f, 0.f);

#pragma unroll
    for (int dy = -1; dy <= 1; ++dy) {
        int r = y + dy;
        if (r < 0 || r >= HH) continue;            // uniform per wave
        const float* row = img + (size_t)r * WW;
        float4 c = *(const float4*)(row + x0);     // aligned 16B load
        float l  = (x0 > 0)        ? row[x0 - 1] : 0.f;   // halo (L1/L2 hit)
        float rr = (x0 + 4 < WW)   ? row[x0 + 4] : 0.f;
        const float kl = k[(dy + 1) * 3 + 0];
        const float kc = k[(dy + 1) * 3 + 1];
        const float kr = k[(dy + 1) * 3 + 2];
        acc.x = fmaf(kl, l,   fmaf(kc, c.x, fmaf(kr, c.y, acc.x)));
        acc.y = fmaf(kl, c.x, fmaf(kc, c.y, fmaf(kr, c.z, acc.y)));
        acc.z = fmaf(kl, c.y, fmaf(kc, c.z, fmaf(kr, c.w, acc.z)));
        acc.w = fmaf(kl, c.z, fmaf(kc, c.w, fmaf(kr, rr,  acc.w)));
    }

    *(float4*)(out + (size_t)tid * 4) = acc;       // tid*4 == b*H*W + y*W + x0
}

extern "C" void kernel_launch(void* const* d_in, const int* in_sizes, int n_in,
                              void* d_out, int out_size, void* d_ws, size_t ws_size,
                              hipStream_t stream) {
    const float* in   = (const float*)d_in[0];   // [64,1,512,512]
    const float* wgt  = (const float*)d_in[1];   // [1,9]
    const float* wfac = (const float*)d_in[2];   // [1,1]
    float* out = (float*)d_out;                  // [1,64,1,512,512]

    const int total_v4 = BB * HH * W4;           // 4,194,304
    const int block = 256;
    const int grid = total_v4 / block;           // 16384
    gauss3x3_kernel<<<grid, block, 0, stream>>>(in, wgt, wfac, out);
}

// Round 2
// 119.317 us; speedup vs baseline: 1.0916x; 1.0916x over previous
//
#include <hip/hip_runtime.h>

// Gaussian 3x3 conv forward, B=64, C=1, H=W=512, N_MULT=1.
// taps = max(rint(clamp(w,0.001,0.999)*clamp(wf,1.001,254.999)), 0.001), then
// 3x3 conv, zero padding=1. Output [1,64,1,512,512] fp32 (flat layout == input).
//
// Row-blocked: each thread computes a 4-row x 4-col (float4) output tile.
// Loads 6 input rows once (vs 3x redundant in the 1-row version), 6 dwordx4 +
// 12 scalar halos + 4 dwordx4 stores per 64 B of output.

#define BB 64
#define HH 512
#define WW 512
#define W4 (WW / 4)   // 128 float4 per row
#define RR 4          // output rows per thread

__global__ __launch_bounds__(256) void gauss3x3_kernel(
    const float* __restrict__ in,     // [B,1,H,W]
    const float* __restrict__ wgt,    // [1,9]
    const float* __restrict__ wfac,   // [1,1]
    float* __restrict__ out)          // [1,B,1,H,W]
{
    // Derive the 9 taps (redundant per thread; scalar broadcast loads).
    float wf = fminf(fmaxf(wfac[0], 1.001f), 254.999f);
    float k[9];
#pragma unroll
    for (int i = 0; i < 9; ++i) {
        float wc = fminf(fmaxf(wgt[i], 0.001f), 0.999f);
        k[i] = fmaxf(rintf(wc * wf), 0.001f);   // rintf = round-half-even = jnp.round
    }

    int tid   = blockIdx.x * blockDim.x + threadIdx.x;   // [0, B*(H/RR)*W4)
    int x4    = tid & (W4 - 1);              // lane-varying: column (float4 units)
    int strip = (tid >> 7) & (HH / RR - 1);  // wave-uniform: 4-row strip
    int b     = tid >> 14;                   // wave-uniform: batch
    if (b >= BB) return;

    const int y0 = strip * RR;
    const int x0 = x4 * 4;
    const float* img  = in  + (size_t)b * HH * WW;
    float*       outp = out + (size_t)b * HH * WW;

    float4 acc[RR];
#pragma unroll
    for (int i = 0; i < RR; ++i) acc[i] = make_float4(0.f, 0.f, 0.f, 0.f);

    // Input rows j=0..5 map to ry = y0-1+j. Input row j contributes to:
    //   out i=j   with tap row 0 (k[0..2], dy=-1)
    //   out i=j-1 with tap row 1 (k[3..5], dy= 0)
    //   out i=j-2 with tap row 2 (k[6..8], dy=+1)
#pragma unroll
    for (int j = 0; j < RR + 2; ++j) {
        const int ry = y0 - 1 + j;
        float4 c = make_float4(0.f, 0.f, 0.f, 0.f);
        float  l = 0.f, r = 0.f;
        if (ry >= 0 && ry < HH) {            // wave-uniform branch
            const float* row = img + (size_t)ry * WW;
            c = *(const float4*)(row + x0);  // aligned 16B load
            l = (x0 > 0)      ? row[x0 - 1] : 0.f;   // L1-hot halo gathers
            r = (x0 + 4 < WW) ? row[x0 + 4] : 0.f;
        }
#pragma unroll
        for (int t = 0; t < 3; ++t) {
            const int i = j - t;
            if (i >= 0 && i < RR) {
                const float kl = k[t * 3 + 0];
                const float kc = k[t * 3 + 1];
                const float kr = k[t * 3 + 2];
                acc[i].x = fmaf(kl, l,   fmaf(kc, c.x, fmaf(kr, c.y, acc[i].x)));
                acc[i].y = fmaf(kl, c.x, fmaf(kc, c.y, fmaf(kr, c.z, acc[i].y)));
                acc[i].z = fmaf(kl, c.y, fmaf(kc, c.z, fmaf(kr, c.w, acc[i].z)));
                acc[i].w = fmaf(kl, c.z, fmaf(kc, c.w, fmaf(kr, r,   acc[i].w)));
            }
        }
    }

#pragma unroll
    for (int i = 0; i < RR; ++i)
        *(float4*)(outp + (size_t)(y0 + i) * WW + x0) = acc[i];
}

extern "C" void kernel_launch(void* const* d_in, const int* in_sizes, int n_in,
                              void* d_out, int out_size, void* d_ws, size_t ws_size,
                              hipStream_t stream) {
    const float* in   = (const float*)d_in[0];   // [64,1,512,512]
    const float* wgt  = (const float*)d_in[1];   // [1,9]
    const float* wfac = (const float*)d_in[2];   // [1,1]
    float* out = (float*)d_out;                  // [1,64,1,512,512]

    const int total = BB * (HH / RR) * W4;       // 1,048,576 threads
    const int block = 256;
    const int grid  = total / block;             // 4096
    gauss3x3_kernel<<<grid, block, 0, stream>>>(in, wgt, wfac, out);
}

// Round 4
// 110.541 us; speedup vs baseline: 1.1783x; 1.0794x over previous
//
#include <hip/hip_runtime.h>

// Gaussian 3x3 conv forward, B=64, C=1, H=W=512, N_MULT=1.
// taps = max(rint(clamp(w,0.001,0.999)*clamp(wf,1.001,254.999)), 0.001), then
// 3x3 conv, zero padding=1. Output [1,64,1,512,512] fp32 (flat layout == input).
//
// Row-blocked 8x: each thread computes an 8-row x 4-col (float4) output tile.
// Horizontal halos come from cross-lane shuffles (c.w of lane-1 / c.x of lane+1);
// only wave-edge lanes (0 / 63) issue a 1-active-lane scalar load. This removes
// the 2-per-row stride-16B scalar gathers that cost full dwordx4 TA time.
// Output uses non-temporal stores (no reuse; keep L2 for the input rows).

#define BB 64
#define HH 512
#define WW 512
#define W4 (WW / 4)   // 128 float4 per row
#define RR 8          // output rows per thread

typedef float vfloat4 __attribute__((ext_vector_type(4)));  // clang vector: OK for nontemporal builtin

__global__ __launch_bounds__(256) void gauss3x3_kernel(
    const float* __restrict__ in,     // [B,1,H,W]
    const float* __restrict__ wgt,    // [1,9]
    const float* __restrict__ wfac,   // [1,1]
    float* __restrict__ out)          // [1,B,1,H,W]
{
    // Derive the 9 taps (redundant per thread; scalar broadcast loads).
    float wf = fminf(fmaxf(wfac[0], 1.001f), 254.999f);
    float k[9];
#pragma unroll
    for (int i = 0; i < 9; ++i) {
        float wc = fminf(fmaxf(wgt[i], 0.001f), 0.999f);
        k[i] = fmaxf(rintf(wc * wf), 0.001f);   // rintf = round-half-even = jnp.round
    }

    const int tid   = blockIdx.x * blockDim.x + threadIdx.x; // [0, B*(H/RR)*W4)
    const int lane  = threadIdx.x & 63;
    const int x4    = tid & (W4 - 1);              // lane-varying: column (float4)
    const int strip = (tid >> 7) & (HH / RR - 1);  // wave-uniform: 8-row strip
    const int b     = tid >> 13;                   // wave-uniform: batch
    if (b >= BB) return;

    const int y0 = strip * RR;
    const int x0 = x4 * 4;
    const float* img  = in  + (size_t)b * HH * WW;
    float*       outp = out + (size_t)b * HH * WW;

    float4 acc[RR];
#pragma unroll
    for (int i = 0; i < RR; ++i) acc[i] = make_float4(0.f, 0.f, 0.f, 0.f);

    // Input rows j=0..RR+1 map to ry = y0-1+j. Input row j contributes to:
    //   out i=j   with tap row 0 (k[0..2], dy=-1)
    //   out i=j-1 with tap row 1 (k[3..5], dy= 0)
    //   out i=j-2 with tap row 2 (k[6..8], dy=+1)
#pragma unroll
    for (int j = 0; j < RR + 2; ++j) {
        const int ry = y0 - 1 + j;
        float4 c = make_float4(0.f, 0.f, 0.f, 0.f);
        float  l = 0.f, r = 0.f;
        if (ry >= 0 && ry < HH) {                  // wave-uniform branch
            const float* row = img + (size_t)ry * WW;
            c = *(const float4*)(row + x0);        // aligned 16B load
            l = __shfl_up(c.w, 1);                 // lane-1's last element
            r = __shfl_down(c.x, 1);               // lane+1's first element
            if (lane == 0)                         // wave-edge fix-up (1 active lane)
                l = (x0 > 0) ? row[x0 - 1] : 0.f;
            if (lane == 63)
                r = (x0 + 4 < WW) ? row[x0 + 4] : 0.f;
        }
#pragma unroll
        for (int t = 0; t < 3; ++t) {
            const int i = j - t;
            if (i >= 0 && i < RR) {
                const float kl = k[t * 3 + 0];
                const float kc = k[t * 3 + 1];
                const float kr = k[t * 3 + 2];
                acc[i].x = fmaf(kl, l,   fmaf(kc, c.x, fmaf(kr, c.y, acc[i].x)));
                acc[i].y = fmaf(kl, c.x, fmaf(kc, c.y, fmaf(kr, c.z, acc[i].y)));
                acc[i].z = fmaf(kl, c.y, fmaf(kc, c.z, fmaf(kr, c.w, acc[i].z)));
                acc[i].w = fmaf(kl, c.z, fmaf(kc, c.w, fmaf(kr, r,   acc[i].w)));
            }
        }
    }

#pragma unroll
    for (int i = 0; i < RR; ++i) {
        vfloat4* dst = (vfloat4*)(outp + (size_t)(y0 + i) * WW + x0);
        vfloat4 v = { acc[i].x, acc[i].y, acc[i].z, acc[i].w };
        __builtin_nontemporal_store(v, dst);       // streamed; output has no reuse
    }
}

extern "C" void kernel_launch(void* const* d_in, const int* in_sizes, int n_in,
                              void* d_out, int out_size, void* d_ws, size_t ws_size,
                              hipStream_t stream) {
    const float* in   = (const float*)d_in[0];   // [64,1,512,512]
    const float* wgt  = (const float*)d_in[1];   // [1,9]
    const float* wfac = (const float*)d_in[2];   // [1,1]
    float* out = (float*)d_out;                  // [1,64,1,512,512]

    const int total = BB * (HH / RR) * W4;       // 524,288 threads
    const int block = 256;
    const int grid  = total / block;             // 2048
    gauss3x3_kernel<<<grid, block, 0, stream>>>(in, wgt, wfac, out);
}